// Round 13
// baseline (371.170 us; speedup 1.0000x reference)
//
#include <hip/hip_runtime.h>
#include <hip/hip_cooperative_groups.h>

namespace cg = cooperative_groups;

#define IS 256
#define FCOUNT 4096
#define NEARP 0.1f
#define FARP 100.0f
#define TINYF 1e-12f
#define CAP 192          // per-8x8-bin capacity (mean ~35; tail ≪ CAP)
#define GCAP 128         // per-image sliver-list capacity
#define DET_GLOBAL 1e-5f // |det| below this -> per-image list (escape unbounded)
#define ZEPS 2e-4f       // early-z slack (zp >= min(z)-5e-5 proven; 4x margin)

// Value barrier: pins a value in a VGPR; no transform across it.
__device__ __forceinline__ float frn(float r) { asm("" : "+v"(r)); return r; }
__device__ __forceinline__ float mulrn(float a, float b) { return frn(a * b); }
__device__ __forceinline__ float addrn(float a, float b) { return frn(a + b); }
__device__ __forceinline__ float subrn(float a, float b) { return frn(a - b); }
__device__ __forceinline__ float divrn(float a, float b) { return frn(a / b); }
__device__ __forceinline__ float fmarn(float a, float b, float c) {
    return frn(__builtin_fmaf(a, b, c));
}

// One cooperative dispatch, three phases (R12 logic, fused):
//  Z: grid-stride zero of counts+gcount        (replaces memset dispatch)
//  B: per-face constants + 8x8-px binning      (R12 bin_kernel, verified)
//  R: wave-private quadrant raster + shading   (R12 raster_kernel, verified)
// grid.sync() + __threadfence() between phases (device scope -> cross-XCD
// visibility per G16). Numerics: R6-verified contracted chain throughout.
__global__ __launch_bounds__(256) void fused_kernel(
    const float* __restrict__ faces,
    const float* __restrict__ textures,
    float4* __restrict__ cA, float4* __restrict__ cB, float4* __restrict__ cC,
    int* __restrict__ counts, int* __restrict__ lists,
    int* __restrict__ gcount, int* __restrict__ glist,
    float* __restrict__ out, int B, int F, int nbins)
{
    const int tid = threadIdx.x;
    const int nthreads = gridDim.x * 256;
    cg::grid_group grid = cg::this_grid();

    // ---------------- Phase Z: zero counts (+ gcount, contiguous) ----------
    for (int zi = blockIdx.x * 256 + tid; zi < nbins + B; zi += nthreads)
        counts[zi] = 0;
    __threadfence();
    grid.sync();

    // ---------------- Phase B: constants + binning -------------------------
    for (int gid = blockIdx.x * 256 + tid; gid < B * F; gid += nthreads) {
        const int b = gid >> 12, f = gid & (FCOUNT - 1);   // F == 4096
        const float* fp = faces + (size_t)gid * 9;
        const float x0 = fp[0], y0 = fp[1], z0 = fp[2];
        const float x1 = fp[3], y1 = fp[4], z1 = fp[5];
        const float x2 = fp[6], y2 = fp[7], z2 = fp[8];

        // Verified contracted numerics: C = fma(xa, yb, -(xb*ya)).
        const float A0 = subrn(x2, x1), B0 = subrn(y1, y2);
        const float C0 = fmarn(x1, y2, -mulrn(x2, y1));
        const float A1 = subrn(x0, x2), B1 = subrn(y2, y0);
        const float C1 = fmarn(x2, y0, -mulrn(x0, y2));
        const float A2 = subrn(x1, x0), B2 = subrn(y0, y1);
        const float C2 = fmarn(x0, y1, -mulrn(x1, y0));
        cA[gid] = make_float4(A0, B0, C0, A1);
        cB[gid] = make_float4(B1, C1, A2, B2);
        cC[gid] = make_float4(C2, z0, z1, z2);

        // Conservative dilation: escape <= ~6e-8/|det|; 2e-3 + 3e-7/|det|
        // (5x safety, <= 0.032). |det| < 1e-5 -> per-image global list.
        const float det = (x1 - x0) * (y2 - y0) - (x2 - x0) * (y1 - y0);
        const float ad = fabsf(det);
        if (ad < DET_GLOBAL) {
            const int pos = atomicAdd(&gcount[b], 1);
            if (pos < GCAP) glist[b * GCAP + pos] = f;
            continue;
        }
        const float d = 2e-3f + 3e-7f / ad;   // <= 0.032
        const float lox = fminf(x0, fminf(x1, x2)) - d;
        const float hix = fmaxf(x0, fmaxf(x1, x2)) + d;
        const float loy = fminf(y0, fminf(y1, y2)) - d;
        const float hiy = fmaxf(y0, fmaxf(y1, y2)) + d;
        // 8-px tile t: xp in [(16t+1-256)/256, (16t+15-256)/256]; dilation
        // (>= 0.5 NDC px) dwarfs the ~1e-7 fp slack of these bounds.
        int tx0 = (int)ceilf ((256.f * lox + 241.f) * (1.f / 16.f));
        int tx1 = (int)floorf((256.f * hix + 255.f) * (1.f / 16.f));
        int ty0 = (int)ceilf ((256.f * loy + 241.f) * (1.f / 16.f));
        int ty1 = (int)floorf((256.f * hiy + 255.f) * (1.f / 16.f));
        tx0 = max(tx0, 0); tx1 = min(tx1, 31);
        ty0 = max(ty0, 0); ty1 = min(ty1, 31);
        for (int ty = ty0; ty <= ty1; ++ty)
            for (int tx = tx0; tx <= tx1; ++tx) {
                const int t = (b * 32 + ty) * 32 + tx;
                const int pos = atomicAdd(&counts[t], 1);
                if (pos < CAP) lists[(size_t)t * CAP + pos] = f;
            }
    }
    __threadfence();   // make lists/cA/cB/cC visible device-wide (cross-XCD)
    grid.sync();

    // ---------------- Phase R: rasterize my block's 16x16 tile -------------
    const int lane = tid & 63;
    const int w    = tid >> 6;
    const int b    = blockIdx.x >> 8;
    const int tile = blockIdx.x & 255;
    const int qtx  = 2 * (tile & 15) + (w & 1);    // 8-px tile coords (0..31)
    const int qty  = 2 * (tile >> 4) + (w >> 1);
    const int qbin = (b * 32 + qty) * 32 + qtx;
    const int px   = qtx * 8 + (lane & 7);
    const int py   = qty * 8 + (lane >> 3);
    const float xp = (float)(2 * px + 1 - IS) * (1.0f / IS);  // exact (/2^8)
    const float yp = (float)(2 * py + 1 - IS) * (1.0f / IS);  // exact

    __shared__ float4 s_a[4][64];
    __shared__ float4 s_b[4][64];
    __shared__ float4 s_c[4][64];
    __shared__ int    s_i[4][64];

    float bestz = FARP;
    int   besti = -1;

    const int cnt  = min(counts[qbin], CAP);
    const int gcnt = min(gcount[b], GCAP);
    const int total = cnt + gcnt;
    const int* mylist = lists + (size_t)qbin * CAP;
    const int* gl     = glist + b * GCAP;
    const int fb = b * F;

    for (int cb = 0; cb < total; cb += 64) {
        const int m = min(total - cb, 64);
        if (lane < m) {
            const int k = cb + lane;
            const int f = (k < cnt) ? mylist[k] : gl[k - cnt];
            s_a[w][lane] = cA[fb + f];
            s_b[w][lane] = cB[fb + f];
            s_c[w][lane] = cC[fb + f];
            s_i[w][lane] = f;
        }
        __builtin_amdgcn_wave_barrier();  // order LDS write -> read (free)

        for (int j = 0; j < m; ++j) {
            const float4 fa  = s_a[w][j];
            const float4 fb4 = s_b[w][j];
            const float4 fc  = s_c[w][j];
            // Contracted: w = fma(yp, A, xp*B) + C
            const float w0 = addrn(fmarn(yp, fa.x, mulrn(xp, fa.y)), fa.z);
            const float w1 = addrn(fmarn(yp, fa.w, mulrn(xp, fb4.x)), fb4.y);
            const float w2 = addrn(fmarn(yp, fb4.z, mulrn(xp, fb4.w)), fc.x);
            const float det = addrn(addrn(w0, w1), w2);
            bool ins;
            if (det > TINYF)       ins = (w0 > 0.f) && (w1 > 0.f) && (w2 > 0.f);
            else if (det < -TINYF) ins = (w0 < 0.f) && (w1 < 0.f) && (w2 < 0.f);
            else                   ins = false;
            // Early-z: a face with min(z) > bestz+ZEPS can't win or tie.
            const float minz = fminf(fminf(fc.y, fc.z), fc.w);
            if (ins && minz <= bestz + ZEPS) {
                float n0 = divrn(w0, det), n1 = divrn(w1, det), n2 = divrn(w2, det);
                n0 = frn(fminf(fmaxf(n0, 0.f), 1.f));
                n1 = frn(fminf(fmaxf(n1, 0.f), 1.f));
                n2 = frn(fminf(fmaxf(n2, 0.f), 1.f));
                float s = addrn(addrn(n0, n1), n2);
                s = (s > TINYF) ? s : 1.0f;
                n0 = divrn(n0, s); n1 = divrn(n1, s); n2 = divrn(n2, s);
                float iz = addrn(addrn(divrn(n0, fc.y), divrn(n1, fc.z)),
                                 divrn(n2, fc.w));
                iz = (fabsf(iz) > TINYF) ? iz : 1.0f;
                const float zp = divrn(1.0f, iz);
                if (zp > NEARP && zp < FARP) {
                    const int fi = s_i[w][j];
                    if (zp < bestz || (zp == bestz && fi < besti)) {
                        bestz = zp;
                        besti = fi;
                    }
                }
            }
        }
        __builtin_amdgcn_wave_barrier();  // scan done before next staging
    }

    // Shade the winning face (R6-verified chain, unchanged).
    const float* fbase = faces + (size_t)b * F * 9;
    float r = 0.f, g = 0.f, bch = 0.f, alpha = 0.f, depth = FARP;
    if (besti >= 0) {
        const float* fp = fbase + (size_t)besti * 9;
        const float x0 = fp[0], y0 = fp[1], z0 = fp[2];
        const float x1 = fp[3], y1 = fp[4], z1 = fp[5];
        const float x2 = fp[6], y2 = fp[7], z2 = fp[8];
        const float w0 = addrn(fmarn(yp, subrn(x2, x1), mulrn(xp, subrn(y1, y2))),
                               fmarn(x1, y2, -mulrn(x2, y1)));
        const float w1 = addrn(fmarn(yp, subrn(x0, x2), mulrn(xp, subrn(y2, y0))),
                               fmarn(x2, y0, -mulrn(x0, y2)));
        const float w2 = addrn(fmarn(yp, subrn(x1, x0), mulrn(xp, subrn(y0, y1))),
                               fmarn(x0, y1, -mulrn(x1, y0)));
        const float det = addrn(addrn(w0, w1), w2);
        const float sd = (fabsf(det) > TINYF) ? det : 1.0f;
        float n0 = divrn(w0, sd), n1 = divrn(w1, sd), n2 = divrn(w2, sd);
        n0 = frn(fminf(fmaxf(n0, 0.f), 1.f));
        n1 = frn(fminf(fmaxf(n1, 0.f), 1.f));
        n2 = frn(fminf(fmaxf(n2, 0.f), 1.f));
        float s = addrn(addrn(n0, n1), n2);
        s = (s > TINYF) ? s : 1.0f;
        n0 = divrn(n0, s); n1 = divrn(n1, s); n2 = divrn(n2, s);
        float iz = addrn(addrn(divrn(n0, z0), divrn(n1, z1)), divrn(n2, z2));
        iz = (fabsf(iz) > TINYF) ? iz : 1.0f;
        const float zp = divrn(1.0f, iz);
        depth = zp;

        const float t0 = fminf(fmaxf(divrn(mulrn(mulrn(n0, 3.0f), zp), z0), 0.f), 2.999f);
        const float t1 = fminf(fmaxf(divrn(mulrn(mulrn(n1, 3.0f), zp), z1), 0.f), 2.999f);
        const float t2 = fminf(fmaxf(divrn(mulrn(mulrn(n2, 3.0f), zp), z2), 0.f), 2.999f);
        const float l0 = floorf(t0), l1 = floorf(t1), l2 = floorf(t2);
        const float fr0 = subrn(t0, l0), fr1 = subrn(t1, l1), fr2 = subrn(t2, l2);
        const int i0 = (int)l0, i1 = (int)l1, i2 = (int)l2;

        const float* tx = textures + (size_t)(b * F + besti) * 64 * 3;
        for (int d0 = 0; d0 < 2; ++d0)
            for (int d1 = 0; d1 < 2; ++d1)
                for (int d2 = 0; d2 < 2; ++d2) {
                    const float wg = mulrn(mulrn(d0 ? fr0 : subrn(1.0f, fr0),
                                                 d1 ? fr1 : subrn(1.0f, fr1)),
                                           d2 ? fr2 : subrn(1.0f, fr2));
                    const float* tp = tx + ((i0 + d0) * 16 + (i1 + d1) * 4 + (i2 + d2)) * 3;
                    r   = addrn(r,   mulrn(wg, tp[0]));
                    g   = addrn(g,   mulrn(wg, tp[1]));
                    bch = addrn(bch, mulrn(wg, tp[2]));
                }
        alpha = 1.0f;
    }

    float* op = out + (((size_t)b * IS + py) * IS + px) * 5;
    op[0] = r;
    op[1] = g;
    op[2] = bch;
    op[3] = alpha;
    op[4] = depth;
}

extern "C" void kernel_launch(void* const* d_in, const int* in_sizes, int n_in,
                              void* d_out, int out_size, void* d_ws, size_t ws_size,
                              hipStream_t stream) {
    const float* faces    = (const float*)d_in[0];
    const float* textures = (const float*)d_in[1];
    float* out = (float*)d_out;
    int F = FCOUNT;
    int B = in_sizes[0] / (F * 9);
    int nbins = B * 1024;                // 32x32 bins per image

    // ws layout (cA 16B-aligned; counts & gcount contiguous for Phase Z).
    int* counts = (int*)d_ws;                       // nbins ints
    int* gcount = counts + nbins;                   // B ints
    int* glist  = gcount + B;                       // B*GCAP ints
    int* lists  = glist + B * GCAP;                 // nbins*CAP ints
    float4* cA  = (float4*)(lists + (size_t)nbins * CAP);   // B*F float4
    float4* cB  = cA + (size_t)B * F;
    float4* cC  = cB + (size_t)B * F;

    void* args[] = {
        (void*)&faces, (void*)&textures,
        (void*)&cA, (void*)&cB, (void*)&cC,
        (void*)&counts, (void*)&lists, (void*)&gcount, (void*)&glist,
        (void*)&out, (void*)&B, (void*)&F, (void*)&nbins
    };
    hipLaunchCooperativeKernel((const void*)fused_kernel,
                               dim3(B * 256), dim3(256), args, 0, stream);
}

// Round 14
// 189.108 us; speedup vs baseline: 1.9627x; 1.9627x over previous
//
#include <hip/hip_runtime.h>

#define IS 256
#define FCOUNT 4096
#define NEARP 0.1f
#define FARP 100.0f
#define TINYF 1e-12f
#define CAP 192          // per-8x8-bin capacity (mean ~27; tail ≪ CAP)
#define GCAP 128         // per-image sliver-list capacity
#define DET_GLOBAL 1e-5f // |det| below this -> per-image list (escape unbounded)
#define ZEPS 2e-4f       // early-z slack (zp >= min(z)-5e-5 proven; 4x margin)
#define NBLK 512         // 2 blocks/CU: 8 waves + 27KB LDS per CU -> co-resident

// Value barrier: pins a value in a VGPR; no transform across it.
__device__ __forceinline__ float frn(float r) { asm("" : "+v"(r)); return r; }
__device__ __forceinline__ float mulrn(float a, float b) { return frn(a * b); }
__device__ __forceinline__ float addrn(float a, float b) { return frn(a + b); }
__device__ __forceinline__ float subrn(float a, float b) { return frn(a - b); }
__device__ __forceinline__ float divrn(float a, float b) { return frn(a / b); }
__device__ __forceinline__ float fmarn(float a, float b, float c) {
    return frn(__builtin_fmaf(a, b, c));
}

// Lightweight device-wide barrier (R13's cg::grid.sync cost ~135us each; this
// is ~4us): thread-0 arrival atomicAdd + s_sleep poll; threadfence gives
// release/acquire semantics across XCD L2s (G16). Counter monotonic: target
// NBLK for barrier 1, 2*NBLK for barrier 2 — no reset needed.
__device__ __forceinline__ void gbar(int* bar, int target) {
    __syncthreads();
    if (threadIdx.x == 0) {
        __threadfence();                      // release
        atomicAdd(bar, 1);
        while (atomicAdd(bar, 0) < target)    // atomic load (uncached)
            __builtin_amdgcn_s_sleep(8);
        __threadfence();                      // acquire
    }
    __syncthreads();
}

// One persistent dispatch, three phases (R12 logic, verified numerics):
//  Z: zero counts+gcount  ->  bar  ->  B: constants+binning  ->  bar  ->
//  R: wave-private quadrant raster + shading (grid-stride over tiles).
__global__ __launch_bounds__(256) void fused_kernel(
    const float* __restrict__ faces,
    const float* __restrict__ textures,
    float4* __restrict__ cA, float4* __restrict__ cB, float4* __restrict__ cC,
    int* __restrict__ bar, int* __restrict__ counts, int* __restrict__ lists,
    int* __restrict__ gcount, int* __restrict__ glist,
    float* __restrict__ out, int B, int F, int nbins)
{
    const int tid = threadIdx.x;

    // ---------------- Phase Z: zero counts (+ gcount, contiguous) ----------
    for (int zi = blockIdx.x * 256 + tid; zi < nbins + B; zi += NBLK * 256)
        counts[zi] = 0;
    gbar(bar, NBLK);

    // ---------------- Phase B: constants + binning (R12-verified) ----------
    for (int gid = blockIdx.x * 256 + tid; gid < B * F; gid += NBLK * 256) {
        const int b = gid >> 12, f = gid & (FCOUNT - 1);   // F == 4096
        const float* fp = faces + (size_t)gid * 9;
        const float x0 = fp[0], y0 = fp[1], z0 = fp[2];
        const float x1 = fp[3], y1 = fp[4], z1 = fp[5];
        const float x2 = fp[6], y2 = fp[7], z2 = fp[8];

        // Verified contracted numerics: C = fma(xa, yb, -(xb*ya)).
        const float A0 = subrn(x2, x1), B0 = subrn(y1, y2);
        const float C0 = fmarn(x1, y2, -mulrn(x2, y1));
        const float A1 = subrn(x0, x2), B1 = subrn(y2, y0);
        const float C1 = fmarn(x2, y0, -mulrn(x0, y2));
        const float A2 = subrn(x1, x0), B2 = subrn(y0, y1);
        const float C2 = fmarn(x0, y1, -mulrn(x1, y0));
        cA[gid] = make_float4(A0, B0, C0, A1);
        cB[gid] = make_float4(B1, C1, A2, B2);
        cC[gid] = make_float4(C2, z0, z1, z2);

        // Conservative dilation: escape <= ~6e-8/|det|; 2e-3 + 3e-7/|det|
        // (5x safety, <= 0.032). |det| < 1e-5 -> per-image global list.
        const float det = (x1 - x0) * (y2 - y0) - (x2 - x0) * (y1 - y0);
        const float ad = fabsf(det);
        if (ad < DET_GLOBAL) {
            const int pos = atomicAdd(&gcount[b], 1);
            if (pos < GCAP) glist[b * GCAP + pos] = f;
            continue;
        }
        const float d = 2e-3f + 3e-7f / ad;   // <= 0.032
        const float lox = fminf(x0, fminf(x1, x2)) - d;
        const float hix = fmaxf(x0, fmaxf(x1, x2)) + d;
        const float loy = fminf(y0, fminf(y1, y2)) - d;
        const float hiy = fmaxf(y0, fmaxf(y1, y2)) + d;
        // 8-px tile t: xp in [(16t+1-256)/256, (16t+15-256)/256]; dilation
        // (>= 0.5 NDC px) dwarfs the ~1e-7 fp slack of these bounds.
        int tx0 = (int)ceilf ((256.f * lox + 241.f) * (1.f / 16.f));
        int tx1 = (int)floorf((256.f * hix + 255.f) * (1.f / 16.f));
        int ty0 = (int)ceilf ((256.f * loy + 241.f) * (1.f / 16.f));
        int ty1 = (int)floorf((256.f * hiy + 255.f) * (1.f / 16.f));
        tx0 = max(tx0, 0); tx1 = min(tx1, 31);
        ty0 = max(ty0, 0); ty1 = min(ty1, 31);
        for (int ty = ty0; ty <= ty1; ++ty)
            for (int tx = tx0; tx <= tx1; ++tx) {
                const int t = (b * 32 + ty) * 32 + tx;
                const int pos = atomicAdd(&counts[t], 1);
                if (pos < CAP) lists[(size_t)t * CAP + pos] = f;
            }
    }
    gbar(bar, 2 * NBLK);

    // ---------------- Phase R: raster, grid-stride over 16x16 tiles --------
    const int lane = tid & 63;
    const int w    = tid >> 6;

    __shared__ float4 s_a[4][64];
    __shared__ float4 s_b[4][64];
    __shared__ float4 s_c[4][64];
    __shared__ int    s_i[4][64];

    for (int t = blockIdx.x; t < B * 256; t += NBLK) {
        const int b    = t >> 8;
        const int tile = t & 255;
        const int qtx  = 2 * (tile & 15) + (w & 1);    // 8-px tile coords
        const int qty  = 2 * (tile >> 4) + (w >> 1);
        const int qbin = (b * 32 + qty) * 32 + qtx;
        const int px   = qtx * 8 + (lane & 7);
        const int py   = qty * 8 + (lane >> 3);
        const float xp = (float)(2 * px + 1 - IS) * (1.0f / IS);  // exact
        const float yp = (float)(2 * py + 1 - IS) * (1.0f / IS);  // exact

        float bestz = FARP;
        int   besti = -1;

        const int cnt  = min(counts[qbin], CAP);
        const int gcnt = min(gcount[b], GCAP);
        const int total = cnt + gcnt;
        const int* mylist = lists + (size_t)qbin * CAP;
        const int* gl     = glist + b * GCAP;
        const int fb = b * F;

        for (int cb = 0; cb < total; cb += 64) {
            const int m = min(total - cb, 64);
            if (lane < m) {
                const int k = cb + lane;
                const int f = (k < cnt) ? mylist[k] : gl[k - cnt];
                s_a[w][lane] = cA[fb + f];
                s_b[w][lane] = cB[fb + f];
                s_c[w][lane] = cC[fb + f];
                s_i[w][lane] = f;
            }
            __builtin_amdgcn_wave_barrier();  // order LDS write -> read

            for (int j = 0; j < m; ++j) {
                const float4 fa  = s_a[w][j];
                const float4 fb4 = s_b[w][j];
                const float4 fc  = s_c[w][j];
                // Contracted: w = fma(yp, A, xp*B) + C
                const float w0 = addrn(fmarn(yp, fa.x, mulrn(xp, fa.y)), fa.z);
                const float w1 = addrn(fmarn(yp, fa.w, mulrn(xp, fb4.x)), fb4.y);
                const float w2 = addrn(fmarn(yp, fb4.z, mulrn(xp, fb4.w)), fc.x);
                const float det = addrn(addrn(w0, w1), w2);
                bool ins;
                if (det > TINYF)       ins = (w0 > 0.f) && (w1 > 0.f) && (w2 > 0.f);
                else if (det < -TINYF) ins = (w0 < 0.f) && (w1 < 0.f) && (w2 < 0.f);
                else                   ins = false;
                // Early-z: min(z) > bestz+ZEPS can't win or tie.
                const float minz = fminf(fminf(fc.y, fc.z), fc.w);
                if (ins && minz <= bestz + ZEPS) {
                    float n0 = divrn(w0, det), n1 = divrn(w1, det), n2 = divrn(w2, det);
                    n0 = frn(fminf(fmaxf(n0, 0.f), 1.f));
                    n1 = frn(fminf(fmaxf(n1, 0.f), 1.f));
                    n2 = frn(fminf(fmaxf(n2, 0.f), 1.f));
                    float s = addrn(addrn(n0, n1), n2);
                    s = (s > TINYF) ? s : 1.0f;
                    n0 = divrn(n0, s); n1 = divrn(n1, s); n2 = divrn(n2, s);
                    float iz = addrn(addrn(divrn(n0, fc.y), divrn(n1, fc.z)),
                                     divrn(n2, fc.w));
                    iz = (fabsf(iz) > TINYF) ? iz : 1.0f;
                    const float zp = divrn(1.0f, iz);
                    if (zp > NEARP && zp < FARP) {
                        const int fi = s_i[w][j];
                        if (zp < bestz || (zp == bestz && fi < besti)) {
                            bestz = zp;
                            besti = fi;
                        }
                    }
                }
            }
            __builtin_amdgcn_wave_barrier();  // scan done before next staging
        }

        // Shade the winning face (R6-verified chain, unchanged).
        const float* fbase = faces + (size_t)b * F * 9;
        float r = 0.f, g = 0.f, bch = 0.f, alpha = 0.f, depth = FARP;
        if (besti >= 0) {
            const float* fp = fbase + (size_t)besti * 9;
            const float x0 = fp[0], y0 = fp[1], z0 = fp[2];
            const float x1 = fp[3], y1 = fp[4], z1 = fp[5];
            const float x2 = fp[6], y2 = fp[7], z2 = fp[8];
            const float w0 = addrn(fmarn(yp, subrn(x2, x1), mulrn(xp, subrn(y1, y2))),
                                   fmarn(x1, y2, -mulrn(x2, y1)));
            const float w1 = addrn(fmarn(yp, subrn(x0, x2), mulrn(xp, subrn(y2, y0))),
                                   fmarn(x2, y0, -mulrn(x0, y2)));
            const float w2 = addrn(fmarn(yp, subrn(x1, x0), mulrn(xp, subrn(y0, y1))),
                                   fmarn(x0, y1, -mulrn(x1, y0)));
            const float det = addrn(addrn(w0, w1), w2);
            const float sd = (fabsf(det) > TINYF) ? det : 1.0f;
            float n0 = divrn(w0, sd), n1 = divrn(w1, sd), n2 = divrn(w2, sd);
            n0 = frn(fminf(fmaxf(n0, 0.f), 1.f));
            n1 = frn(fminf(fmaxf(n1, 0.f), 1.f));
            n2 = frn(fminf(fmaxf(n2, 0.f), 1.f));
            float s = addrn(addrn(n0, n1), n2);
            s = (s > TINYF) ? s : 1.0f;
            n0 = divrn(n0, s); n1 = divrn(n1, s); n2 = divrn(n2, s);
            float iz = addrn(addrn(divrn(n0, z0), divrn(n1, z1)), divrn(n2, z2));
            iz = (fabsf(iz) > TINYF) ? iz : 1.0f;
            const float zp = divrn(1.0f, iz);
            depth = zp;

            const float t0 = fminf(fmaxf(divrn(mulrn(mulrn(n0, 3.0f), zp), z0), 0.f), 2.999f);
            const float t1 = fminf(fmaxf(divrn(mulrn(mulrn(n1, 3.0f), zp), z1), 0.f), 2.999f);
            const float t2 = fminf(fmaxf(divrn(mulrn(mulrn(n2, 3.0f), zp), z2), 0.f), 2.999f);
            const float l0 = floorf(t0), l1 = floorf(t1), l2 = floorf(t2);
            const float fr0 = subrn(t0, l0), fr1 = subrn(t1, l1), fr2 = subrn(t2, l2);
            const int i0 = (int)l0, i1 = (int)l1, i2 = (int)l2;

            const float* tx = textures + (size_t)(b * F + besti) * 64 * 3;
            for (int d0 = 0; d0 < 2; ++d0)
                for (int d1 = 0; d1 < 2; ++d1)
                    for (int d2 = 0; d2 < 2; ++d2) {
                        const float wg = mulrn(mulrn(d0 ? fr0 : subrn(1.0f, fr0),
                                                     d1 ? fr1 : subrn(1.0f, fr1)),
                                               d2 ? fr2 : subrn(1.0f, fr2));
                        const float* tp = tx + ((i0 + d0) * 16 + (i1 + d1) * 4 + (i2 + d2)) * 3;
                        r   = addrn(r,   mulrn(wg, tp[0]));
                        g   = addrn(g,   mulrn(wg, tp[1]));
                        bch = addrn(bch, mulrn(wg, tp[2]));
                    }
            alpha = 1.0f;
        }

        float* op = out + (((size_t)b * IS + py) * IS + px) * 5;
        op[0] = r;
        op[1] = g;
        op[2] = bch;
        op[3] = alpha;
        op[4] = depth;
    }
}

extern "C" void kernel_launch(void* const* d_in, const int* in_sizes, int n_in,
                              void* d_out, int out_size, void* d_ws, size_t ws_size,
                              hipStream_t stream) {
    const float* faces    = (const float*)d_in[0];
    const float* textures = (const float*)d_in[1];
    float* out = (float*)d_out;
    int F = FCOUNT;
    int B = in_sizes[0] / (F * 9);
    int nbins = B * 1024;                // 32x32 bins per image

    // ws layout: bar(4 ints pad) | counts(nbins) | gcount(B) | glist(B*GCAP)
    //            | lists(nbins*CAP) | cA | cB | cC   (cA stays 16B-aligned:
    //            total preceding int count is a multiple of 4).
    int* bar    = (int*)d_ws;                       // 4 ints (use [0])
    int* counts = bar + 4;                          // nbins ints
    int* gcount = counts + nbins;                   // B ints
    int* glist  = gcount + B;                       // B*GCAP ints
    int* lists  = glist + B * GCAP;                 // nbins*CAP ints
    float4* cA  = (float4*)(lists + (size_t)nbins * CAP);   // B*F float4
    float4* cB  = cA + (size_t)B * F;
    float4* cC  = cB + (size_t)B * F;

    hipMemsetAsync(bar, 0, 16, stream);   // only the barrier counter
    fused_kernel<<<dim3(NBLK), dim3(256), 0, stream>>>(
        faces, textures, cA, cB, cC, bar, counts, lists, gcount, glist,
        out, B, F, nbins);
}